// Round 7
// baseline (204.180 us; speedup 1.0000x reference)
//
#include <hip/hip_runtime.h>
#include <stdint.h>

#define BN 4
#define CD 256
#define ND 4096
#define NK 32            // key-tile size in attention
#define WPK_M 65536      // u16 per packed weight matrix (8 kc * 16 nt * 512)

typedef unsigned short u16;
typedef short bfrag __attribute__((ext_vector_type(8)));  // 8 bf16 = 4 VGPR
typedef float ffrag __attribute__((ext_vector_type(4)));  // MFMA C/D frag

__device__ __forceinline__ float bf2f(u16 u) {
  union { unsigned int i; float f; } v;
  v.i = ((unsigned int)u) << 16;
  return v.f;
}
__device__ __forceinline__ u16 f2bf(float f) {
  union { float f; unsigned int i; } v;
  v.f = f;
  return (u16)((v.i + 0x7FFFu + ((v.i >> 16) & 1u)) >> 16);  // RNE
}
// packed f32x2 -> bf16x2 (RNE), 1 VALU op for 2 values; low 16 = a
// (low-half=first-arg semantics HW-validated: round-6 proj3 passed bit-identical)
__device__ __forceinline__ unsigned int cvtpk(float a, float b) {
  unsigned int r;
  asm("v_cvt_pk_bf16_f32 %0, %1, %2" : "=v"(r) : "v"(a), "v"(b));
  return r;
}
// async global->LDS DMA, 16B per lane; LDS dest = wave-uniform base + lane*16
__device__ __forceinline__ void gload_lds(const u16* g, u16* l) {
  __builtin_amdgcn_global_load_lds(
      (const __attribute__((address_space(1))) void*)g,
      (__attribute__((address_space(3))) void*)l, 16, 0, 0);
}

// ---------- pack weights into MFMA fragment order ----------
// frag-block (m, kc, nt): 1 KB; lane l holds W_m[nt*16+(l&15)][kc*32+(l>>4)*8+j]
// at offset l*16 B. Serves B-operand (QK) and A-operand (V) identically.
__global__ __launch_bounds__(256) void k_packW(
    const float* __restrict__ Wq, const float* __restrict__ Wk,
    const float* __restrict__ Wv, u16* __restrict__ Wpk) {
  int idx = blockIdx.x * 256 + threadIdx.x;  // 0..24575
  int lane = idx & 63;
  int fb = idx >> 6;                         // 0..383
  int nt = fb & 15, kc = (fb >> 4) & 7, m = fb >> 7;
  const float* W = (m == 0) ? Wq : ((m == 1) ? Wk : Wv);
  const float* s = W + (size_t)(nt * 16 + (lane & 15)) * CD + kc * 32 + (lane >> 4) * 8;
  u16* d = Wpk + (size_t)m * WPK_M + ((size_t)(kc * 16 + nt)) * 512 + lane * 8;
  float4 v0 = *(const float4*)(s);
  float4 v1 = *(const float4*)(s + 4);
  ushort4 o0, o1;
  o0.x = f2bf(v0.x); o0.y = f2bf(v0.y); o0.z = f2bf(v0.z); o0.w = f2bf(v0.w);
  o1.x = f2bf(v1.x); o1.y = f2bf(v1.y); o1.z = f2bf(v1.z); o1.w = f2bf(v1.w);
  *(ushort4*)(d) = o0;
  *(ushort4*)(d + 4) = o1;
}

// ---------- merged projections: grid (64, 4, 3), packed-frag weights ------
// z in {0,1}: Q/K path, m0 = (y*64+x)*64. z == 2: V path, n0s = x*64, b = y.
// All f32->bf16 via v_cvt_pk_bf16_f32 (RNE, bit-identical to scalar path).
__global__ __launch_bounds__(256, 4) void k_proj3(
    const float* __restrict__ x, const float* __restrict__ y,
    const u16* __restrict__ Wpk, const float* __restrict__ bq,
    const float* __restrict__ bk, const float* __restrict__ bv,
    u16* __restrict__ Qb, u16* __restrict__ Kb, u16* __restrict__ Vb) {
  __shared__ alignas(16) union {
    u16 S1[64][264];   // input^T staging AND Q/K output staging (row-major)
    u16 Vt[256][72];   // V output staging [d][n_local], 144B rows (16B-align)
  } sm;
  int t = threadIdx.x, w = t >> 6, l = t & 63;
  int lane16 = l & 15, quad = l >> 4;
  int zz = blockIdx.z;

  if (zz < 2) {
    // ------- Q/K path -------
    int m0 = (blockIdx.y * 64 + blockIdx.x) * 64;  // [0, 16384)
    int b = m0 >> 12, nsp = m0 & 4095;
    const float* src = (zz ? y : x) + (size_t)b * CD * ND;
    const float* bias = zz ? bk : bq;
    u16* Cd = (zz ? Kb : Qb) + (size_t)m0 * CD;
    const u16* Wz = Wpk + (size_t)zz * WPK_M;

    {
      int u = t & 15, grp = t >> 4;
#pragma unroll
      for (int it = 0; it < 8; ++it) {
        int c = it * 32 + grp * 2;
        const float* col0 = src + (size_t)c * ND + nsp;
        const float* col1 = col0 + ND;
#pragma unroll
        for (int j = 0; j < 4; ++j) {
          int row = j * 16 + u;
          unsigned int pk = cvtpk(col0[row], col1[row]);
          *(unsigned int*)&sm.S1[row][c] = pk;
        }
      }
    }
    __syncthreads();

    bfrag af[8];
#pragma unroll
    for (int kc = 0; kc < 8; ++kc)
      af[kc] = *(const bfrag*)&sm.S1[w * 16 + lane16][kc * 32 + quad * 8];

    ffrag acc[16];
#pragma unroll
    for (int i = 0; i < 16; ++i) acc[i] = ffrag{0.f, 0.f, 0.f, 0.f};

#pragma unroll
    for (int kc = 0; kc < 8; ++kc) {
      const u16* base = Wz + ((size_t)kc * 16) * 512 + l * 8;
#pragma unroll
      for (int nt = 0; nt < 16; ++nt) {
        bfrag bfr = *(const bfrag*)(base + nt * 512);
        acc[nt] = __builtin_amdgcn_mfma_f32_16x16x32_bf16(af[kc], bfr, acc[nt], 0, 0, 0);
      }
    }
    __syncthreads();  // all waves done reading S1
#pragma unroll
    for (int nt = 0; nt < 16; ++nt) {
      int col = nt * 16 + lane16;
      float bcol = bias[col];
      unsigned int p01 = cvtpk(acc[nt][0] + bcol, acc[nt][1] + bcol);
      unsigned int p23 = cvtpk(acc[nt][2] + bcol, acc[nt][3] + bcol);
      int r0 = w * 16 + quad * 4;
      sm.S1[r0 + 0][col] = (u16)p01;
      sm.S1[r0 + 1][col] = (u16)(p01 >> 16);
      sm.S1[r0 + 2][col] = (u16)p23;
      sm.S1[r0 + 3][col] = (u16)(p23 >> 16);
    }
    __syncthreads();
#pragma unroll
    for (int it = 0; it < 8; ++it) {
      int i = it * 256 + t;          // 0..2047 -> 64 rows x 32 16B-chunks
      int row = i >> 5, chunk = i & 31;
      *(uint4*)(Cd + (size_t)row * CD + chunk * 8) =
          *(const uint4*)&sm.S1[row][chunk * 8];
    }
  } else {
    // ------- V path -------
    int n0s = blockIdx.x * 64;
    int b = blockIdx.y;
    const float* src = y + (size_t)b * CD * ND;
    u16* Cd = Vb + (size_t)b * CD * ND;
    const u16* Wz = Wpk + (size_t)2 * WPK_M;

    {
      int u = t & 15, grp = t >> 4;
#pragma unroll
      for (int it = 0; it < 8; ++it) {
        int c = it * 32 + grp * 2;
        const float* col0 = src + (size_t)c * ND + n0s;
        const float* col1 = col0 + ND;
#pragma unroll
        for (int j = 0; j < 4; ++j) {
          int row = j * 16 + u;
          unsigned int pk = cvtpk(col0[row], col1[row]);
          *(unsigned int*)&sm.S1[row][c] = pk;
        }
      }
    }
    __syncthreads();

    bfrag bfr8[8];
#pragma unroll
    for (int kc = 0; kc < 8; ++kc)
      bfr8[kc] = *(const bfrag*)&sm.S1[w * 16 + lane16][kc * 32 + quad * 8];

    ffrag o[16];
#pragma unroll
    for (int i = 0; i < 16; ++i) o[i] = ffrag{0.f, 0.f, 0.f, 0.f};

#pragma unroll
    for (int kc = 0; kc < 8; ++kc) {
      const u16* base = Wz + ((size_t)kc * 16) * 512 + l * 8;
#pragma unroll
      for (int mt = 0; mt < 16; ++mt) {
        bfrag af = *(const bfrag*)(base + mt * 512);
        o[mt] = __builtin_amdgcn_mfma_f32_16x16x32_bf16(af, bfr8[kc], o[mt], 0, 0, 0);
      }
    }
    __syncthreads();  // all waves done reading S1
#pragma unroll
    for (int mt = 0; mt < 16; ++mt) {
      int d0 = mt * 16 + quad * 4;
      unsigned int p01 = cvtpk(o[mt][0] + bv[d0 + 0], o[mt][1] + bv[d0 + 1]);
      unsigned int p23 = cvtpk(o[mt][2] + bv[d0 + 2], o[mt][3] + bv[d0 + 3]);
      int nloc = w * 16 + lane16;
      sm.Vt[d0 + 0][nloc] = (u16)p01;
      sm.Vt[d0 + 1][nloc] = (u16)(p01 >> 16);
      sm.Vt[d0 + 2][nloc] = (u16)p23;
      sm.Vt[d0 + 3][nloc] = (u16)(p23 >> 16);
    }
    __syncthreads();
#pragma unroll
    for (int it = 0; it < 8; ++it) {
      int i = it * 256 + t;          // 0..2047 -> 256 d x 8 16B-chunks
      int d = i >> 3, off = (i & 7) * 8;
      *(uint4*)(Cd + (size_t)d * ND + n0s + off) =
          *(const uint4*)&sm.Vt[d][off];
    }
  }
}

// ---------- flash attention, split-K, async-DMA double-buffered ----------
// Q,K: [B*N][C]; Vt: [B][C][N]. 128 q-rows/block, 4 waves x 2 m-tiles.
// SWAPPED QK^T: s2 = mfma(K, Q) = S^T, so q is lane-local (q = l&15) and the
// softmax P redistribution is done entirely in registers (cvt_pk + shfl),
// removing the Ps LDS write->wait->read serialization between QK and PV.
// V MUST be LDS-staged (round-3: direct-L2 V = +64us). No setprio (round-4).
union SmemU {
  struct {
    u16 Ks[2][NK][256];   // 32,768 B  chunk^=(row&7) swizzle
    u16 Vs[2][CD][NK];    // 32,768 B  chunk^=((d>>1)&3) swizzle
  } a;                     // 65,536 B
  u16 ot[CD][136];         // 69,632 B  epilogue O^T staging
};

template <int NS>
__global__ __launch_bounds__(256, 2) void k_attn(
    const u16* __restrict__ Q, const u16* __restrict__ K,
    const u16* __restrict__ Vt, u16* __restrict__ O01,
    u16* __restrict__ O23, float* __restrict__ Lpart) {
  constexpr int NIT = ND / NS / NK;
  __shared__ alignas(16) SmemU sm;
  int b = blockIdx.y, q0 = blockIdx.x * 128, z = blockIdx.z;
  int t = threadIdx.x, w = t >> 6, l = t & 63;
  int lane16 = l & 15, quad = l >> 4;
  const float scale = 0.0625f;  // 256^-0.5

  // Q frags: rows q0 + (w*2+mi)*16 + lane16 (serve as B-operand after swap)
  bfrag qf[2][8];
#pragma unroll
  for (int mi = 0; mi < 2; ++mi) {
    const u16* Qrow =
        Q + ((size_t)b * ND + q0 + (w * 2 + mi) * 16 + lane16) * CD;
#pragma unroll
    for (int kc = 0; kc < 8; ++kc)
      qf[mi][kc] = *(const bfrag*)(Qrow + kc * 32 + quad * 8);
  }

  ffrag o[2][16];
#pragma unroll
  for (int mi = 0; mi < 2; ++mi)
#pragma unroll
    for (int i = 0; i < 16; ++i) o[mi][i] = ffrag{0.f, 0.f, 0.f, 0.f};
  float lsum[2] = {0.f, 0.f};  // per-lane q = l&15 partial (summed over quads at end)

  const u16* Kb = K + ((size_t)b * ND + z * (ND / NS)) * CD;
  const u16* Vb = Vt + (size_t)b * CD * ND + z * (ND / NS);

  auto stage = [&](int kt2) {
    int dbuf = kt2 & 1;
    const u16* Kt = Kb + (size_t)kt2 * NK * CD;
    const u16* Vtt = Vb + kt2 * NK;
#pragma unroll
    for (int p = 0; p < 4; ++p) {
      int r = p * 8 + w * 2 + (l >> 5);
      int j = (l & 31) ^ (r & 7);
      gload_lds(Kt + (size_t)r * CD + j * 8, &sm.a.Ks[dbuf][p * 8 + w * 2][0]);
    }
#pragma unroll
    for (int p = 0; p < 4; ++p) {
      int dd = p * 64 + w * 16 + (l >> 2);
      int j = (l & 3) ^ ((dd >> 1) & 3);
      gload_lds(Vtt + (size_t)dd * ND + j * 8, &sm.a.Vs[dbuf][p * 64 + w * 16][0]);
    }
  };

  stage(0);
  for (int kt = 0; kt < NIT; ++kt) {
    int dbuf = kt & 1;
    __syncthreads();  // drains DMA for buf dbuf; recycling of dbuf^1 is safe
    if (kt + 1 < NIT) stage(kt + 1);  // async into other buffer, no wait

    // S^T = K Q^T  (2 m-tiles x 2 key-tiles); lane: q = l&15, k = tt*16+quad*4+r
    ffrag s2[2][2];
#pragma unroll
    for (int mi = 0; mi < 2; ++mi)
#pragma unroll
      for (int tt = 0; tt < 2; ++tt) s2[mi][tt] = ffrag{0.f, 0.f, 0.f, 0.f};
#pragma unroll
    for (int kc = 0; kc < 8; ++kc) {
      bfrag kf0, kf1;
      {
        int r = lane16;
        int cp = (kc * 4 + quad) ^ (r & 7);
        kf0 = *(const bfrag*)&sm.a.Ks[dbuf][r][cp * 8];
        int r1 = 16 + lane16;
        int cp1 = (kc * 4 + quad) ^ (r1 & 7);
        kf1 = *(const bfrag*)&sm.a.Ks[dbuf][r1][cp1 * 8];
      }
#pragma unroll
      for (int mi = 0; mi < 2; ++mi) {
        s2[mi][0] = __builtin_amdgcn_mfma_f32_16x16x32_bf16(kf0, qf[mi][kc],
                                                            s2[mi][0], 0, 0, 0);
        s2[mi][1] = __builtin_amdgcn_mfma_f32_16x16x32_bf16(kf1, qf[mi][kc],
                                                            s2[mi][1], 0, 0, 0);
      }
    }

    // softmax + in-register P redistribution (no LDS, no ordering stall).
    // Target A-frag: lane wants P[q=l&15][k' = quad*8+j], j=0..7.
    // Source: lane (q, sigma) holds k = tt*16 + sigma*4 + r.
    // word w0,w1 <- sigma_a = 2*(quad&1); w2,w3 <- sigma_b = sigma_a+1;
    // a-half (tt=0) for quad<2, b-half (tt=1) for quad>=2.
    bfrag pf[2];
#pragma unroll
    for (int mi = 0; mi < 2; ++mi) {
      float p0[4], p1[4];
#pragma unroll
      for (int r = 0; r < 4; ++r) {
        p0[r] = __expf(s2[mi][0][r] * scale);
        p1[r] = __expf(s2[mi][1][r] * scale);
        lsum[mi] += p0[r] + p1[r];
      }
      unsigned int a0 = cvtpk(p0[0], p0[1]);
      unsigned int a1 = cvtpk(p0[2], p0[3]);
      unsigned int b0 = cvtpk(p1[0], p1[1]);
      unsigned int b1 = cvtpk(p1[2], p1[3]);
      int srcA = lane16 | ((quad & 1) << 5);  // lane of sigma_a
      int srcB = srcA | 16;                   // lane of sigma_b
      unsigned int Aa0 = (unsigned int)__shfl((int)a0, srcA);
      unsigned int Ab0 = (unsigned int)__shfl((int)b0, srcA);
      unsigned int Aa1 = (unsigned int)__shfl((int)a1, srcA);
      unsigned int Ab1 = (unsigned int)__shfl((int)b1, srcA);
      unsigned int Ba0 = (unsigned int)__shfl((int)a0, srcB);
      unsigned int Bb0 = (unsigned int)__shfl((int)b0, srcB);
      unsigned int Ba1 = (unsigned int)__shfl((int)a1, srcB);
      unsigned int Bb1 = (unsigned int)__shfl((int)b1, srcB);
      bool lo = quad < 2;
      union { unsigned int wd[4]; bfrag f; } up;
      up.wd[0] = lo ? Aa0 : Ab0;
      up.wd[1] = lo ? Aa1 : Ab1;
      up.wd[2] = lo ? Ba0 : Bb0;
      up.wd[3] = lo ? Ba1 : Bb1;
      pf[mi] = up.f;
    }

    // O += P V  (16 d-tiles, V-frag shared across both m-tiles)
#pragma unroll
    for (int dt = 0; dt < 16; ++dt) {
      int dd = dt * 16 + lane16;
      int cp = quad ^ ((dd >> 1) & 3);
      bfrag vf = *(const bfrag*)&sm.a.Vs[dbuf][dd][cp * 8];
      o[0][dt] = __builtin_amdgcn_mfma_f32_16x16x32_bf16(pf[0], vf, o[0][dt], 0, 0, 0);
      o[1][dt] = __builtin_amdgcn_mfma_f32_16x16x32_bf16(pf[1], vf, o[1][dt], 0, 0, 0);
    }
  }

  // row-sum: q is lane-local; reduce across the 4 quad lanes
#pragma unroll
  for (int mi = 0; mi < 2; ++mi) {
    lsum[mi] += __shfl_xor(lsum[mi], 16, 64);
    lsum[mi] += __shfl_xor(lsum[mi], 32, 64);
  }
  if (quad == 0) {
#pragma unroll
    for (int mi = 0; mi < 2; ++mi)
      Lpart[((size_t)z * BN + b) * ND + q0 + (w * 2 + mi) * 16 + lane16] =
          lsum[mi];
  }

  __syncthreads();
  // unnormalized O -> transposed bf16 staging ot[d][q_local]
#pragma unroll
  for (int mi = 0; mi < 2; ++mi)
#pragma unroll
    for (int dt = 0; dt < 16; ++dt)
#pragma unroll
      for (int r = 0; r < 4; ++r)
        sm.ot[dt * 16 + lane16][(w * 2 + mi) * 16 + quad * 4 + r] =
            f2bf(o[mi][dt][r]);
  __syncthreads();
  const size_t SZc = (size_t)BN * ND * CD;
  u16* Op = ((z < 2) ? O01 : O23) + (size_t)(z & 1) * SZc;
#pragma unroll
  for (int it = 0; it < 16; ++it) {
    int c = it * 256 + t;
    int dd = c >> 4, co = (c & 15) * 8;
    size_t g = ((size_t)b * CD + dd) * ND + q0 + co;
    *(uint4*)(Op + g) = *(const uint4*)&sm.ot[dd][co];
  }
}

// ---------- combine partials + residual ----------
template <int NS>
__global__ __launch_bounds__(256) void k_combine(
    const u16* __restrict__ O01, const u16* __restrict__ O23,
    const float* __restrict__ L, const float* __restrict__ x,
    float* __restrict__ out) {
  const size_t SZc = (size_t)BN * ND * CD;
  size_t e = ((size_t)blockIdx.x * 256 + threadIdx.x) * 8;
  int n = (int)(e & (ND - 1));
  int b = (int)(e >> 20);  // C*N = 2^20
  float ls[8] = {0, 0, 0, 0, 0, 0, 0, 0};
  float acc[8] = {0, 0, 0, 0, 0, 0, 0, 0};
#pragma unroll
  for (int z = 0; z < NS; ++z) {
    const float* Lr = L + ((size_t)z * BN + b) * ND + n;
    float4 l0 = *(const float4*)(Lr);
    float4 l1 = *(const float4*)(Lr + 4);
    ls[0] += l0.x; ls[1] += l0.y; ls[2] += l0.z; ls[3] += l0.w;
    ls[4] += l1.x; ls[5] += l1.y; ls[6] += l1.z; ls[7] += l1.w;
    const u16* Oz = ((z < 2) ? O01 : O23) + (size_t)(z & 1) * SZc + e;
    union { uint4 q; u16 s[8]; } u;
    u.q = *(const uint4*)Oz;
#pragma unroll
    for (int j = 0; j < 8; ++j) acc[j] += bf2f(u.s[j]);
  }
  float4 x0 = *(const float4*)(x + e);
  float4 x1 = *(const float4*)(x + e + 4);
  float4 r0, r1;
  r0.x = x0.x + acc[0] / ls[0];
  r0.y = x0.y + acc[1] / ls[1];
  r0.z = x0.z + acc[2] / ls[2];
  r0.w = x0.w + acc[3] / ls[3];
  r1.x = x1.x + acc[4] / ls[4];
  r1.y = x1.y + acc[5] / ls[5];
  r1.z = x1.z + acc[6] / ls[6];
  r1.w = x1.w + acc[7] / ls[7];
  *(float4*)(out + e) = r0;
  *(float4*)(out + e + 4) = r1;
}

extern "C" void kernel_launch(void* const* d_in, const int* in_sizes, int n_in,
                              void* d_out, int out_size, void* d_ws, size_t ws_size,
                              hipStream_t stream) {
  const float* x  = (const float*)d_in[0];
  const float* y  = (const float*)d_in[1];
  const float* Wq = (const float*)d_in[2];
  const float* bq = (const float*)d_in[3];
  const float* Wk = (const float*)d_in[4];
  const float* bk = (const float*)d_in[5];
  const float* Wv = (const float*)d_in[6];
  const float* bv = (const float*)d_in[7];
  float* out = (float*)d_out;
  u16* ws = (u16*)d_ws;
  const size_t SZ = (size_t)BN * ND * CD;  // 4,194,304 elems per tensor
  u16* Qb = ws;
  u16* Kb = Qb + SZ;
  u16* Vb = Kb + SZ;
  u16* Ob = Vb + SZ;  // NS partials, contiguous
  // NS=4: 7*SZ bf16 + 4*BN*ND fp32 (L) + 384 KB packed W
  const size_t need4 = 7 * SZ * sizeof(u16) +
                       (size_t)4 * BN * ND * sizeof(float) +
                       (size_t)3 * WPK_M * sizeof(u16);
  const bool big = ws_size >= need4;  // constant across calls (graph-safe)
  const int cgrid = (int)(SZ / (256 * 8));  // 2048 blocks (out = SZ floats)

  if (big) {
    float* Lp = (float*)(Ob + 4 * SZ);
    u16* Wpk = (u16*)(Lp + (size_t)4 * BN * ND);
    k_packW<<<dim3(96), 256, 0, stream>>>(Wq, Wk, Wv, Wpk);
    k_proj3<<<dim3(64, 4, 3), 256, 0, stream>>>(x, y, Wpk, bq, bk, bv,
                                                Qb, Kb, Vb);
    k_attn<4><<<dim3(ND / 128, BN, 4), 256, 0, stream>>>(Qb, Kb, Vb, Ob,
                                                         Ob + 2 * SZ, Lp);
    k_combine<4><<<dim3(cgrid), 256, 0, stream>>>(Ob, Ob + 2 * SZ, Lp, x, out);
  } else {
    float* Lp = (float*)(Ob + 2 * SZ);
    u16* Wpk = (u16*)(Lp + (size_t)2 * BN * ND);
    k_packW<<<dim3(96), 256, 0, stream>>>(Wq, Wk, Wv, Wpk);
    k_proj3<<<dim3(64, 4, 3), 256, 0, stream>>>(x, y, Wpk, bq, bk, bv,
                                                Qb, Kb, Vb);
    k_attn<2><<<dim3(ND / 128, BN, 2), 256, 0, stream>>>(Qb, Kb, Vb, Ob, Ob, Lp);
    k_combine<2><<<dim3(cgrid), 256, 0, stream>>>(Ob, Ob, Lp, x, out);
  }
}

// Round 8
// 191.385 us; speedup vs baseline: 1.0669x; 1.0669x over previous
//
#include <hip/hip_runtime.h>
#include <stdint.h>

#define BN 4
#define CD 256
#define ND 4096
#define NK 32            // key-tile size in attention
#define WPK_M 65536      // u16 per packed weight matrix (8 kc * 16 nt * 512)

typedef unsigned short u16;
typedef short bfrag __attribute__((ext_vector_type(8)));  // 8 bf16 = 4 VGPR
typedef float ffrag __attribute__((ext_vector_type(4)));  // MFMA C/D frag

__device__ __forceinline__ float bf2f(u16 u) {
  union { unsigned int i; float f; } v;
  v.i = ((unsigned int)u) << 16;
  return v.f;
}
__device__ __forceinline__ u16 f2bf(float f) {
  union { float f; unsigned int i; } v;
  v.f = f;
  return (u16)((v.i + 0x7FFFu + ((v.i >> 16) & 1u)) >> 16);  // RNE
}
// packed f32x2 -> bf16x2 (RNE), 1 VALU op for 2 values; low 16 = a
__device__ __forceinline__ unsigned int cvtpk(float a, float b) {
  unsigned int r;
  asm("v_cvt_pk_bf16_f32 %0, %1, %2" : "=v"(r) : "v"(a), "v"(b));
  return r;
}
// async global->LDS DMA, 16B per lane; LDS dest = wave-uniform base + lane*16
__device__ __forceinline__ void gload_lds(const u16* g, u16* l) {
  __builtin_amdgcn_global_load_lds(
      (const __attribute__((address_space(1))) void*)g,
      (__attribute__((address_space(3))) void*)l, 16, 0, 0);
}

// ---------- pack weights into MFMA fragment order ----------
__global__ __launch_bounds__(256) void k_packW(
    const float* __restrict__ Wq, const float* __restrict__ Wk,
    const float* __restrict__ Wv, u16* __restrict__ Wpk) {
  int idx = blockIdx.x * 256 + threadIdx.x;  // 0..24575
  int lane = idx & 63;
  int fb = idx >> 6;                         // 0..383
  int nt = fb & 15, kc = (fb >> 4) & 7, m = fb >> 7;
  const float* W = (m == 0) ? Wq : ((m == 1) ? Wk : Wv);
  const float* s = W + (size_t)(nt * 16 + (lane & 15)) * CD + kc * 32 + (lane >> 4) * 8;
  u16* d = Wpk + (size_t)m * WPK_M + ((size_t)(kc * 16 + nt)) * 512 + lane * 8;
  float4 v0 = *(const float4*)(s);
  float4 v1 = *(const float4*)(s + 4);
  ushort4 o0, o1;
  o0.x = f2bf(v0.x); o0.y = f2bf(v0.y); o0.z = f2bf(v0.z); o0.w = f2bf(v0.w);
  o1.x = f2bf(v1.x); o1.y = f2bf(v1.y); o1.z = f2bf(v1.z); o1.w = f2bf(v1.w);
  *(ushort4*)(d) = o0;
  *(ushort4*)(d + 4) = o1;
}

// ---------- merged projections: grid (64, 4, 3), packed-frag weights ------
__global__ __launch_bounds__(256, 4) void k_proj3(
    const float* __restrict__ x, const float* __restrict__ y,
    const u16* __restrict__ Wpk, const float* __restrict__ bq,
    const float* __restrict__ bk, const float* __restrict__ bv,
    u16* __restrict__ Qb, u16* __restrict__ Kb, u16* __restrict__ Vb) {
  __shared__ alignas(16) union {
    u16 S1[64][264];   // input^T staging AND Q/K output staging (row-major)
    u16 Vt[256][72];   // V output staging [d][n_local], 144B rows (16B-align)
  } sm;
  int t = threadIdx.x, w = t >> 6, l = t & 63;
  int lane16 = l & 15, quad = l >> 4;
  int zz = blockIdx.z;

  if (zz < 2) {
    // ------- Q/K path -------
    int m0 = (blockIdx.y * 64 + blockIdx.x) * 64;  // [0, 16384)
    int b = m0 >> 12, nsp = m0 & 4095;
    const float* src = (zz ? y : x) + (size_t)b * CD * ND;
    const float* bias = zz ? bk : bq;
    u16* Cd = (zz ? Kb : Qb) + (size_t)m0 * CD;
    const u16* Wz = Wpk + (size_t)zz * WPK_M;

    {
      int u = t & 15, grp = t >> 4;
#pragma unroll
      for (int it = 0; it < 8; ++it) {
        int c = it * 32 + grp * 2;
        const float* col0 = src + (size_t)c * ND + nsp;
        const float* col1 = col0 + ND;
#pragma unroll
        for (int j = 0; j < 4; ++j) {
          int row = j * 16 + u;
          unsigned int pk = cvtpk(col0[row], col1[row]);
          *(unsigned int*)&sm.S1[row][c] = pk;
        }
      }
    }
    __syncthreads();

    bfrag af[8];
#pragma unroll
    for (int kc = 0; kc < 8; ++kc)
      af[kc] = *(const bfrag*)&sm.S1[w * 16 + lane16][kc * 32 + quad * 8];

    ffrag acc[16];
#pragma unroll
    for (int i = 0; i < 16; ++i) acc[i] = ffrag{0.f, 0.f, 0.f, 0.f};

#pragma unroll
    for (int kc = 0; kc < 8; ++kc) {
      const u16* base = Wz + ((size_t)kc * 16) * 512 + l * 8;
#pragma unroll
      for (int nt = 0; nt < 16; ++nt) {
        bfrag bfr = *(const bfrag*)(base + nt * 512);
        acc[nt] = __builtin_amdgcn_mfma_f32_16x16x32_bf16(af[kc], bfr, acc[nt], 0, 0, 0);
      }
    }
    __syncthreads();  // all waves done reading S1
#pragma unroll
    for (int nt = 0; nt < 16; ++nt) {
      int col = nt * 16 + lane16;
      float bcol = bias[col];
      unsigned int p01 = cvtpk(acc[nt][0] + bcol, acc[nt][1] + bcol);
      unsigned int p23 = cvtpk(acc[nt][2] + bcol, acc[nt][3] + bcol);
      int r0 = w * 16 + quad * 4;
      sm.S1[r0 + 0][col] = (u16)p01;
      sm.S1[r0 + 1][col] = (u16)(p01 >> 16);
      sm.S1[r0 + 2][col] = (u16)p23;
      sm.S1[r0 + 3][col] = (u16)(p23 >> 16);
    }
    __syncthreads();
#pragma unroll
    for (int it = 0; it < 8; ++it) {
      int i = it * 256 + t;          // 0..2047 -> 64 rows x 32 16B-chunks
      int row = i >> 5, chunk = i & 31;
      *(uint4*)(Cd + (size_t)row * CD + chunk * 8) =
          *(const uint4*)&sm.S1[row][chunk * 8];
    }
  } else {
    // ------- V path -------
    int n0s = blockIdx.x * 64;
    int b = blockIdx.y;
    const float* src = y + (size_t)b * CD * ND;
    u16* Cd = Vb + (size_t)b * CD * ND;
    const u16* Wz = Wpk + (size_t)2 * WPK_M;

    {
      int u = t & 15, grp = t >> 4;
#pragma unroll
      for (int it = 0; it < 8; ++it) {
        int c = it * 32 + grp * 2;
        const float* col0 = src + (size_t)c * ND + n0s;
        const float* col1 = col0 + ND;
#pragma unroll
        for (int j = 0; j < 4; ++j) {
          int row = j * 16 + u;
          unsigned int pk = cvtpk(col0[row], col1[row]);
          *(unsigned int*)&sm.S1[row][c] = pk;
        }
      }
    }
    __syncthreads();

    bfrag bfr8[8];
#pragma unroll
    for (int kc = 0; kc < 8; ++kc)
      bfr8[kc] = *(const bfrag*)&sm.S1[w * 16 + lane16][kc * 32 + quad * 8];

    ffrag o[16];
#pragma unroll
    for (int i = 0; i < 16; ++i) o[i] = ffrag{0.f, 0.f, 0.f, 0.f};

#pragma unroll
    for (int kc = 0; kc < 8; ++kc) {
      const u16* base = Wz + ((size_t)kc * 16) * 512 + l * 8;
#pragma unroll
      for (int mt = 0; mt < 16; ++mt) {
        bfrag af = *(const bfrag*)(base + mt * 512);
        o[mt] = __builtin_amdgcn_mfma_f32_16x16x32_bf16(af, bfr8[kc], o[mt], 0, 0, 0);
      }
    }
    __syncthreads();  // all waves done reading S1
#pragma unroll
    for (int mt = 0; mt < 16; ++mt) {
      int d0 = mt * 16 + quad * 4;
      unsigned int p01 = cvtpk(o[mt][0] + bv[d0 + 0], o[mt][1] + bv[d0 + 1]);
      unsigned int p23 = cvtpk(o[mt][2] + bv[d0 + 2], o[mt][3] + bv[d0 + 3]);
      int nloc = w * 16 + lane16;
      sm.Vt[d0 + 0][nloc] = (u16)p01;
      sm.Vt[d0 + 1][nloc] = (u16)(p01 >> 16);
      sm.Vt[d0 + 2][nloc] = (u16)p23;
      sm.Vt[d0 + 3][nloc] = (u16)(p23 >> 16);
    }
    __syncthreads();
#pragma unroll
    for (int it = 0; it < 8; ++it) {
      int i = it * 256 + t;          // 0..2047 -> 256 d x 8 16B-chunks
      int d = i >> 3, off = (i & 7) * 8;
      *(uint4*)(Cd + (size_t)d * ND + n0s + off) =
          *(const uint4*)&sm.Vt[d][off];
    }
  }
}

// ---------- flash attention, split-K, async-DMA double-buffered ----------
// Round-5 body (proven 87us) + XCD-aware block swizzle: all 32 q-blocks of
// one (b,z) group -> one XCD (lid%8 heuristic), so the shared K/V slice is
// HBM-fetched once per group and the per-tile DMA drain hits L2 (~200cy)
// instead of HBM (~900cy). FETCH was 70.5MB vs 25MB ideal = XCD spray.
// V LDS-staged (round-3: direct-L2 = +64us). No setprio (round-4). No
// in-register P (round-7: bpermute uses the same LDS pipe, +12us).
union SmemU {
  struct {
    u16 Ks[2][NK][256];   // 32,768 B  chunk^=(row&7) swizzle
    u16 Vs[2][CD][NK];    // 32,768 B  chunk^=((d>>1)&3) swizzle
    u16 Ps[8][16][36];    //  9,216 B  wave-private P staging, 72B rows
  } a;                     // 74,752 B
  u16 ot[CD][136];         // 69,632 B  epilogue O^T staging
};

template <int NS>
__global__ __launch_bounds__(256, 2) void k_attn(
    const u16* __restrict__ Q, const u16* __restrict__ K,
    const u16* __restrict__ Vt, u16* __restrict__ O01,
    u16* __restrict__ O23, float* __restrict__ Lpart) {
  constexpr int NIT = ND / NS / NK;
  constexpr int NBZ = BN * NS;        // (b,z) groups: 16 (NS=4) or 8 (NS=2)
  __shared__ alignas(16) SmemU sm;
  // XCD-aware swizzle: lid%8 ~ XCD. Pin each (b,z) group to one XCD.
  int lid = blockIdx.x + 32 * (blockIdx.y + BN * blockIdx.z);
  int xcd = lid & 7, j = lid >> 3;
  int bz, qt;
  if (NBZ == 16) { bz = (xcd << 1) | (j & 1); qt = j >> 1; }
  else           { bz = xcd;                  qt = j; }
  int b = bz & (BN - 1), z = bz >> 2;
  int q0 = qt * 128;
  int t = threadIdx.x, w = t >> 6, l = t & 63;
  int lane16 = l & 15, quad = l >> 4;
  const float scale = 0.0625f;  // 256^-0.5

  // Q frags: A-layout rows q0 + (w*2+mi)*16 + lane16
  bfrag qf[2][8];
#pragma unroll
  for (int mi = 0; mi < 2; ++mi) {
    const u16* Qrow =
        Q + ((size_t)b * ND + q0 + (w * 2 + mi) * 16 + lane16) * CD;
#pragma unroll
    for (int kc = 0; kc < 8; ++kc)
      qf[mi][kc] = *(const bfrag*)(Qrow + kc * 32 + quad * 8);
  }

  ffrag o[2][16];
#pragma unroll
  for (int mi = 0; mi < 2; ++mi)
#pragma unroll
    for (int i = 0; i < 16; ++i) o[mi][i] = ffrag{0.f, 0.f, 0.f, 0.f};
  float lsum[2][4] = {{0.f, 0.f, 0.f, 0.f}, {0.f, 0.f, 0.f, 0.f}};

  const u16* Kb = K + ((size_t)b * ND + z * (ND / NS)) * CD;
  const u16* Vb = Vt + (size_t)b * CD * ND + z * (ND / NS);

  auto stage = [&](int kt2) {
    int dbuf = kt2 & 1;
    const u16* Kt = Kb + (size_t)kt2 * NK * CD;
    const u16* Vtt = Vb + kt2 * NK;
#pragma unroll
    for (int p = 0; p < 4; ++p) {
      int r = p * 8 + w * 2 + (l >> 5);
      int jj = (l & 31) ^ (r & 7);
      gload_lds(Kt + (size_t)r * CD + jj * 8, &sm.a.Ks[dbuf][p * 8 + w * 2][0]);
    }
#pragma unroll
    for (int p = 0; p < 4; ++p) {
      int dd = p * 64 + w * 16 + (l >> 2);
      int jj = (l & 3) ^ ((dd >> 1) & 3);
      gload_lds(Vtt + (size_t)dd * ND + jj * 8, &sm.a.Vs[dbuf][p * 64 + w * 16][0]);
    }
  };

  stage(0);
  for (int kt = 0; kt < NIT; ++kt) {
    int dbuf = kt & 1;
    __syncthreads();  // drains DMA for buf dbuf; recycling of dbuf^1 is safe
    if (kt + 1 < NIT) stage(kt + 1);  // async into other buffer, no wait

    // S = Q K^T  (2 m-tiles x 2 key-tiles)
    ffrag s2[2][2];
#pragma unroll
    for (int mi = 0; mi < 2; ++mi)
#pragma unroll
      for (int tt = 0; tt < 2; ++tt) s2[mi][tt] = ffrag{0.f, 0.f, 0.f, 0.f};
#pragma unroll
    for (int kc = 0; kc < 8; ++kc) {
      bfrag kf0, kf1;
      {
        int r = lane16;
        int cp = (kc * 4 + quad) ^ (r & 7);
        kf0 = *(const bfrag*)&sm.a.Ks[dbuf][r][cp * 8];
        int r1 = 16 + lane16;
        int cp1 = (kc * 4 + quad) ^ (r1 & 7);
        kf1 = *(const bfrag*)&sm.a.Ks[dbuf][r1][cp1 * 8];
      }
#pragma unroll
      for (int mi = 0; mi < 2; ++mi) {
        s2[mi][0] = __builtin_amdgcn_mfma_f32_16x16x32_bf16(qf[mi][kc], kf0,
                                                            s2[mi][0], 0, 0, 0);
        s2[mi][1] = __builtin_amdgcn_mfma_f32_16x16x32_bf16(qf[mi][kc], kf1,
                                                            s2[mi][1], 0, 0, 0);
      }
    }

    // fixed-max softmax: p = exp(s*scale); lane-partial sums; P -> LDS
#pragma unroll
    for (int mi = 0; mi < 2; ++mi)
#pragma unroll
      for (int tt = 0; tt < 2; ++tt)
#pragma unroll
        for (int r = 0; r < 4; ++r) {
          float p = __expf(s2[mi][tt][r] * scale);
          lsum[mi][r] += p;
          sm.a.Ps[w * 2 + mi][quad * 4 + r][tt * 16 + lane16] = f2bf(p);
        }
    // wave-private Ps: in-wave LDS ordering suffices, no barrier
    bfrag pf0 = *(const bfrag*)&sm.a.Ps[w * 2 + 0][lane16][quad * 8];
    bfrag pf1 = *(const bfrag*)&sm.a.Ps[w * 2 + 1][lane16][quad * 8];

    // O += P V  (16 d-tiles, V-frag shared across both m-tiles)
#pragma unroll
    for (int dt = 0; dt < 16; ++dt) {
      int dd = dt * 16 + lane16;
      int cp = quad ^ ((dd >> 1) & 3);
      bfrag vf = *(const bfrag*)&sm.a.Vs[dbuf][dd][cp * 8];
      o[0][dt] = __builtin_amdgcn_mfma_f32_16x16x32_bf16(pf0, vf, o[0][dt], 0, 0, 0);
      o[1][dt] = __builtin_amdgcn_mfma_f32_16x16x32_bf16(pf1, vf, o[1][dt], 0, 0, 0);
    }
  }

  // row-sum reduction: 16-lane butterfly within quad groups, once
#pragma unroll
  for (int mi = 0; mi < 2; ++mi)
#pragma unroll
    for (int r = 0; r < 4; ++r) {
#pragma unroll
      for (int off = 1; off < 16; off <<= 1)
        lsum[mi][r] += __shfl_xor(lsum[mi][r], off, 64);
    }
  if (lane16 == 0) {
#pragma unroll
    for (int mi = 0; mi < 2; ++mi)
#pragma unroll
      for (int r = 0; r < 4; ++r)
        Lpart[((size_t)z * BN + b) * ND + q0 + (w * 2 + mi) * 16 + quad * 4 + r] =
            lsum[mi][r];
  }

  __syncthreads();
  // unnormalized O -> transposed bf16 staging ot[d][q_local]
#pragma unroll
  for (int mi = 0; mi < 2; ++mi)
#pragma unroll
    for (int dt = 0; dt < 16; ++dt)
#pragma unroll
      for (int r = 0; r < 4; ++r)
        sm.ot[dt * 16 + lane16][(w * 2 + mi) * 16 + quad * 4 + r] =
            f2bf(o[mi][dt][r]);
  __syncthreads();
  const size_t SZc = (size_t)BN * ND * CD;
  u16* Op = ((z < 2) ? O01 : O23) + (size_t)(z & 1) * SZc;
#pragma unroll
  for (int it = 0; it < 16; ++it) {
    int c = it * 256 + t;
    int dd = c >> 4, co = (c & 15) * 8;
    size_t g = ((size_t)b * CD + dd) * ND + q0 + co;
    *(uint4*)(Op + g) = *(const uint4*)&sm.ot[dd][co];
  }
}

// ---------- combine partials + residual ----------
template <int NS>
__global__ __launch_bounds__(256) void k_combine(
    const u16* __restrict__ O01, const u16* __restrict__ O23,
    const float* __restrict__ L, const float* __restrict__ x,
    float* __restrict__ out) {
  const size_t SZc = (size_t)BN * ND * CD;
  size_t e = ((size_t)blockIdx.x * 256 + threadIdx.x) * 8;
  int n = (int)(e & (ND - 1));
  int b = (int)(e >> 20);  // C*N = 2^20
  float ls[8] = {0, 0, 0, 0, 0, 0, 0, 0};
  float acc[8] = {0, 0, 0, 0, 0, 0, 0, 0};
#pragma unroll
  for (int z = 0; z < NS; ++z) {
    const float* Lr = L + ((size_t)z * BN + b) * ND + n;
    float4 l0 = *(const float4*)(Lr);
    float4 l1 = *(const float4*)(Lr + 4);
    ls[0] += l0.x; ls[1] += l0.y; ls[2] += l0.z; ls[3] += l0.w;
    ls[4] += l1.x; ls[5] += l1.y; ls[6] += l1.z; ls[7] += l1.w;
    const u16* Oz = ((z < 2) ? O01 : O23) + (size_t)(z & 1) * SZc + e;
    union { uint4 q; u16 s[8]; } u;
    u.q = *(const uint4*)Oz;
#pragma unroll
    for (int j = 0; j < 8; ++j) acc[j] += bf2f(u.s[j]);
  }
  float4 x0 = *(const float4*)(x + e);
  float4 x1 = *(const float4*)(x + e + 4);
  float4 r0, r1;
  r0.x = x0.x + acc[0] / ls[0];
  r0.y = x0.y + acc[1] / ls[1];
  r0.z = x0.z + acc[2] / ls[2];
  r0.w = x0.w + acc[3] / ls[3];
  r1.x = x1.x + acc[4] / ls[4];
  r1.y = x1.y + acc[5] / ls[5];
  r1.z = x1.z + acc[6] / ls[6];
  r1.w = x1.w + acc[7] / ls[7];
  *(float4*)(out + e) = r0;
  *(float4*)(out + e + 4) = r1;
}

extern "C" void kernel_launch(void* const* d_in, const int* in_sizes, int n_in,
                              void* d_out, int out_size, void* d_ws, size_t ws_size,
                              hipStream_t stream) {
  const float* x  = (const float*)d_in[0];
  const float* y  = (const float*)d_in[1];
  const float* Wq = (const float*)d_in[2];
  const float* bq = (const float*)d_in[3];
  const float* Wk = (const float*)d_in[4];
  const float* bk = (const float*)d_in[5];
  const float* Wv = (const float*)d_in[6];
  const float* bv = (const float*)d_in[7];
  float* out = (float*)d_out;
  u16* ws = (u16*)d_ws;
  const size_t SZ = (size_t)BN * ND * CD;  // 4,194,304 elems per tensor
  u16* Qb = ws;
  u16* Kb = Qb + SZ;
  u16* Vb = Kb + SZ;
  u16* Ob = Vb + SZ;  // NS partials, contiguous
  // NS=4: 7*SZ bf16 + 4*BN*ND fp32 (L) + 384 KB packed W
  const size_t need4 = 7 * SZ * sizeof(u16) +
                       (size_t)4 * BN * ND * sizeof(float) +
                       (size_t)3 * WPK_M * sizeof(u16);
  const bool big = ws_size >= need4;  // constant across calls (graph-safe)
  const int cgrid = (int)(SZ / (256 * 8));  // 2048 blocks (out = SZ floats)

  if (big) {
    float* Lp = (float*)(Ob + 4 * SZ);
    u16* Wpk = (u16*)(Lp + (size_t)4 * BN * ND);
    k_packW<<<dim3(96), 256, 0, stream>>>(Wq, Wk, Wv, Wpk);
    k_proj3<<<dim3(64, 4, 3), 256, 0, stream>>>(x, y, Wpk, bq, bk, bv,
                                                Qb, Kb, Vb);
    k_attn<4><<<dim3(ND / 128, BN, 4), 256, 0, stream>>>(Qb, Kb, Vb, Ob,
                                                         Ob + 2 * SZ, Lp);
    k_combine<4><<<dim3(cgrid), 256, 0, stream>>>(Ob, Ob + 2 * SZ, Lp, x, out);
  } else {
    float* Lp = (float*)(Ob + 2 * SZ);
    u16* Wpk = (u16*)(Lp + (size_t)2 * BN * ND);
    k_packW<<<dim3(96), 256, 0, stream>>>(Wq, Wk, Wv, Wpk);
    k_proj3<<<dim3(64, 4, 3), 256, 0, stream>>>(x, y, Wpk, bq, bk, bv,
                                                Qb, Kb, Vb);
    k_attn<2><<<dim3(ND / 128, BN, 2), 256, 0, stream>>>(Qb, Kb, Vb, Ob, Ob, Lp);
    k_combine<2><<<dim3(cgrid), 256, 0, stream>>>(Ob, Ob, Lp, x, out);
  }
}